// Round 2
// baseline (407.648 us; speedup 1.0000x reference)
//
#include <hip/hip_runtime.h>
#include <math.h>

// N=64, C=256, T=64, V=25 graph-ODE, 4 fused blocks. bf16 MFMA 32x32x16.
// R4: S=1 slab/WG + manual 40.3 KB LDS layout -> 4 WGs/CU (occupancy 2x).
// R5: Phase-G software pipeline: depth-4 rotating w/y register buffers.
// R6: residual kept in 32 VGPRs (kills 32 ds_read_u16+cvt per blk/thread);
//     barrier moved to just after k-loop so epilogue+w-prefetch+PhaseA of the
//     next block overlap across waves; blk0 w-prefetch hoisted above staging.
#define NN 64
#define CC 256
#define TT 64
#define VV 25

typedef __bf16 bf16;
typedef __attribute__((ext_vector_type(8)))  __bf16 bf16x8;
typedef __attribute__((ext_vector_type(4)))  __bf16 bf16x4;
typedef __attribute__((ext_vector_type(16))) float  f32x16;

#define RS 40    // sres row stride (bf16): 80 B
#define YS 264   // syT row stride (bf16): 528 B

// Manual LDS layout (bytes). syT declared 26 rows; reads from lanes 26..31
// overrun into sAb/sbias (read-only after staging; results masked) - by design.
#define OFF_SRES  0        // 256*40*2  = 20480
#define OFF_SYT   20480    // 26*264*2  = 13728
#define OFF_SAB   34208    // 32*32*2   = 2048
#define OFF_SBIAS 36256    // 4*256*4   = 4096
#define SMEM_BYTES 40352   // <= 40960 -> 4 WGs/CU

// ---- pack the four 256x256 fp32 w into bf16 MFMA A-fragment order ----
// wp[((blk*4+wv)*16+k)*1024 + pair*512 + lane*8 + e]
//   = w_blk[wv*64+pair*32+(lane&31)][k*16+(lane>>5)*8+e]
__global__ void convert_w(const float* __restrict__ w1, const float* __restrict__ w2,
                          const float* __restrict__ w3, const float* __restrict__ w4,
                          bf16* __restrict__ wp) {
    const int gid = blockIdx.x * 256 + threadIdx.x;   // 0..32767
    const int e8  = gid * 8;                          // linear over 4*65536 elems
    const int blk = e8 >> 16;
    const int off = e8 & 65535;
    const int row = off >> 8;
    const int col = off & 255;
    const float* src = (blk == 0) ? w1 : (blk == 1) ? w2 : (blk == 2) ? w3 : w4;
    const float4 f0 = *(const float4*)(src + off);        // coalesced reads
    const float4 f1 = *(const float4*)(src + off + 4);
    bf16x8 o;
    o[0] = (bf16)f0.x; o[1] = (bf16)f0.y; o[2] = (bf16)f0.z; o[3] = (bf16)f0.w;
    o[4] = (bf16)f1.x; o[5] = (bf16)f1.y; o[6] = (bf16)f1.z; o[7] = (bf16)f1.w;
    const int wv = row >> 6, pair = (row >> 5) & 1, l31 = row & 31;
    const int k = col >> 4, lh = (col >> 3) & 1;
    wp += (((size_t)(blk * 4 + wv) * 16 + k) * 1024) + pair * 512 + (lh * 32 + l31) * 8;
    *(bf16x8*)wp = o;
}

#define MFMA(A, B, C) __builtin_amdgcn_mfma_f32_32x32x16_bf16(A, B, C, 0, 0, 0)

__global__ __launch_bounds__(256, 4) void ode_mfma(
    const float* __restrict__ x, const float* __restrict__ Amat,
    const bf16* __restrict__ wp,
    const float* __restrict__ b1, const float* __restrict__ b2,
    const float* __restrict__ b3, const float* __restrict__ b4,
    float* __restrict__ out)
{
    __shared__ __attribute__((aligned(16))) char smem[SMEM_BYTES];
    bf16*  sres  = (bf16*)(smem + OFF_SRES);    // [c][RS]
    bf16*  syT   = (bf16*)(smem + OFF_SYT);     // [v][YS]
    bf16*  sAb   = (bf16*)(smem + OFF_SAB);     // [v][32]
    float* sbias = (float*)(smem + OFF_SBIAS);  // [4][CC]

    const int t    = blockIdx.x;
    const int n    = blockIdx.y;
    const int tid  = threadIdx.x;
    const int wave = tid >> 6;
    const int lane = tid & 63;
    const int lh   = lane >> 5;
    const int l31  = lane & 31;
    const int o0   = wave * 64;

    // ---- blk0 w-prefetch: no LDS dependency, issue before all staging so the
    //      8 global loads complete under the staging phase + barrier. ----
    bf16x8 wA[4], wB[4];
    {
        const bf16* wb0 = wp + ((size_t)wave * 16) * 1024 + lane * 8;
        #pragma unroll
        for (int q = 0; q < 4; ++q) {
            wA[q] = *(const bf16x8*)(wb0 + q * 1024);
            wB[q] = *(const bf16x8*)(wb0 + q * 1024 + 512);
        }
    }

    // ---- stage biases (coalesced) ----
    sbias[0 * CC + tid] = b1[tid];
    sbias[1 * CC + tid] = b2[tid];
    sbias[2 * CC + tid] = b3[tid];
    sbias[3 * CC + tid] = b4[tid];

    // ---- stage A, zero-padded to 32x32 ----
    for (int i = tid; i < 32 * 32; i += 256) {
        const int v = i >> 5, u = i & 31;
        sAb[i] = (v < VV && u < VV) ? (bf16)Amat[v * VV + u] : (bf16)0.f;
    }

    // ---- stage x slab (mostly-coalesced scalar; odd t breaks 8B alignment) ----
    {
        const float* xb = x + ((size_t)n * CC * TT + t) * VV;  // + c*T*V + v
        for (int i = tid; i < CC * VV; i += 256) {
            const int c = i / VV;
            const int v = i - c * VV;
            sres[c * RS + v] = (bf16)xb[(size_t)c * TT * VV + v];
        }
        #pragma unroll
        for (int u = VV; u < 32; ++u) sres[tid * RS + u] = (bf16)0.f;  // tid == c
    }
    __syncthreads();

    // A-matrix B-fragments are constant across blocks: hoist.
    const bf16x8 bfA0 = *(const bf16x8*)&sAb[l31 * 32 + lh * 8];
    const bf16x8 bfA1 = *(const bf16x8*)&sAb[l31 * 32 + 16 + lh * 8];

    // ---- residual in registers: resv[i], i = OT*16 + g*4 + r maps to
    //      o = o0 + OT*32 + 8g + 4lh + r, v = l31. Each thread re-reads in
    //      the epilogue exactly what it wrote last block -> keep in VGPRs.
    //      (v>=VV lanes hold the zero padding; never stored.) ----
    float resv[32];
    #pragma unroll
    for (int i = 0; i < 32; ++i) {
        const int OT = i >> 4, g = (i >> 2) & 3, r = i & 3;
        const int o = o0 + OT * 32 + 8 * g + 4 * lh + r;
        resv[i] = (float)sres[o * RS + l31];
    }

    for (int blk = 0; blk < 4; ++blk) {
        // ===== Phase A: yT[v][c] = sum_u res[c][u] * A[v][u]; 2 c-tiles/wave =====
        // sres rows read here are wave-local (written by this wave's epilogue):
        // no barrier needed for sres, only for syT below.
        #pragma unroll
        for (int i = 0; i < 2; ++i) {
            const int ct = wave * 2 + i;
            const bf16x8 af0 = *(const bf16x8*)&sres[(ct * 32 + l31) * RS + lh * 8];
            const bf16x8 af1 = *(const bf16x8*)&sres[(ct * 32 + l31) * RS + 16 + lh * 8];
            f32x16 d = {};
            d = MFMA(af0, bfA0, d);
            d = MFMA(af1, bfA1, d);
            // D: col v = l31, row c = ct*32 + (reg&3) + 8*(reg>>2) + 4*lh
            if (l31 < VV) {
                #pragma unroll
                for (int g = 0; g < 4; ++g) {
                    bf16x4 p;
                    p[0] = (bf16)d[4 * g];     p[1] = (bf16)d[4 * g + 1];
                    p[2] = (bf16)d[4 * g + 2]; p[3] = (bf16)d[4 * g + 3];
                    *(bf16x4*)&syT[l31 * YS + ct * 32 + 8 * g + 4 * lh] = p;
                }
            }
        }
        __syncthreads();   // syT writes -> k-loop reads

        // ===== Phase G: out[o][v] = relu(sum_c w[o,c] y[c][v] + b[o] + res[o][v]) =====
        const bf16* wbase = wp + ((size_t)(blk * 4 + wave) * 16) * 1024 + lane * 8;

        f32x16 acc0 = {}, acc1 = {};
        bf16x8 yv[4];
        #pragma unroll
        for (int q = 0; q < 4; ++q)
            yv[q] = *(const bf16x8*)&syT[l31 * YS + q * 16 + lh * 8];

        #pragma unroll
        for (int k = 0; k < 16; ++k) {
            const bf16x8 a0 = wA[k & 3];
            const bf16x8 a1 = wB[k & 3];
            const bf16x8 y0 = yv[k & 3];
            if (k < 12) {   // static after full unroll -> registers, no scratch
                wA[k & 3] = *(const bf16x8*)(wbase + (k + 4) * 1024);
                wB[k & 3] = *(const bf16x8*)(wbase + (k + 4) * 1024 + 512);
                yv[k & 3] = *(const bf16x8*)&syT[l31 * YS + (k + 4) * 16 + lh * 8];
            }
            acc0 = MFMA(a0, y0, acc0);
            acc1 = MFMA(a1, y0, acc1);
        }
        __syncthreads();   // syT reads done -> next block's Phase A may overwrite.
                           // Epilogue + next-w-prefetch + Phase A now overlap
                           // across waves inside the barrier window.

        // ---- prefetch next block's w: L2 latency hides under the epilogue ----
        if (blk < 3) {
            const bf16* wn = wp + ((size_t)((blk + 1) * 4 + wave) * 16) * 1024 + lane * 8;
            #pragma unroll
            for (int q = 0; q < 4; ++q) {
                wA[q] = *(const bf16x8*)(wn + q * 1024);
                wB[q] = *(const bf16x8*)(wn + q * 1024 + 512);
            }
        }

        const int v = l31;
        #define EPILOGUE(ACC, OT)                                                   \
            _Pragma("unroll")                                                       \
            for (int g = 0; g < 4; ++g) {                                           \
                const int ob = o0 + (OT) * 32 + 8 * g + 4 * lh;                     \
                const float4 bq = *(const float4*)&sbias[blk * CC + ob];            \
                _Pragma("unroll")                                                   \
                for (int r = 0; r < 4; ++r) {                                       \
                    const int o = ob + r;                                           \
                    const int ri = (OT) * 16 + g * 4 + r;                           \
                    float val = ACC[4 * g + r] + ((const float*)&bq)[r] + resv[ri]; \
                    val = fmaxf(val, 0.f);                                          \
                    resv[ri] = val;                                                 \
                    if (v < VV) {                                                   \
                        if (blk < 3) sres[o * RS + v] = (bf16)val;                  \
                        else out[(((size_t)n * CC + o) * TT + t) * VV + v] = val;   \
                    }                                                               \
                }                                                                   \
            }
        EPILOGUE(acc0, 0)
        EPILOGUE(acc1, 1)
        #undef EPILOGUE
    }
}

extern "C" void kernel_launch(void* const* d_in, const int* in_sizes, int n_in,
                              void* d_out, int out_size, void* d_ws, size_t ws_size,
                              hipStream_t stream) {
    const float* x  = (const float*)d_in[1];
    const float* A  = (const float*)d_in[2];
    const float* w1 = (const float*)d_in[3];
    const float* b1 = (const float*)d_in[4];
    const float* w2 = (const float*)d_in[5];
    const float* b2 = (const float*)d_in[6];
    const float* w3 = (const float*)d_in[7];
    const float* b3 = (const float*)d_in[8];
    const float* w4 = (const float*)d_in[9];
    const float* b4 = (const float*)d_in[10];
    float* out = (float*)d_out;
    bf16* wp = (bf16*)d_ws;   // 512 KB packed w fragments

    convert_w<<<128, 256, 0, stream>>>(w1, w2, w3, w4, wp);
    dim3 grid(TT, NN);        // one WG per (n,t) slab: 4096 WGs
    ode_mfma<<<grid, 256, 0, stream>>>(x, A, wp, b1, b2, b3, b4, out);
}

// Round 3
// 334.374 us; speedup vs baseline: 1.2191x; 1.2191x over previous
//
#include <hip/hip_runtime.h>
#include <math.h>

// N=64, C=256, T=64, V=25 graph-ODE, 4 fused blocks. bf16 MFMA 32x32x16.
// R4: S=1 slab/WG + manual 40.3 KB LDS layout -> 4 WGs/CU (occupancy 2x).
// R5: Phase-G software pipeline: depth-4 rotating w/y register buffers.
// R6: FAILED - resv[32] register residual spilled to scratch (+120MB WRITE).
// R7: revert resv (epilogue reads residual from LDS as in R5); keep barrier
//     moved to just-after-k-loop (syT WAR only; sres is wave-local), next-w
//     prefetch under epilogue+PhaseA window; s_setprio(1) around MFMA loop.
#define NN 64
#define CC 256
#define TT 64
#define VV 25

typedef __bf16 bf16;
typedef __attribute__((ext_vector_type(8)))  __bf16 bf16x8;
typedef __attribute__((ext_vector_type(4)))  __bf16 bf16x4;
typedef __attribute__((ext_vector_type(16))) float  f32x16;

#define RS 40    // sres row stride (bf16): 80 B
#define YS 264   // syT row stride (bf16): 528 B

// Manual LDS layout (bytes). syT declared 26 rows; reads from lanes 26..31
// overrun into sAb/sbias (read-only after staging; results masked) - by design.
#define OFF_SRES  0        // 256*40*2  = 20480
#define OFF_SYT   20480    // 26*264*2  = 13728
#define OFF_SAB   34208    // 32*32*2   = 2048
#define OFF_SBIAS 36256    // 4*256*4   = 4096
#define SMEM_BYTES 40352   // <= 40960 -> 4 WGs/CU

// ---- pack the four 256x256 fp32 w into bf16 MFMA A-fragment order ----
// wp[((blk*4+wv)*16+k)*1024 + pair*512 + lane*8 + e]
//   = w_blk[wv*64+pair*32+(lane&31)][k*16+(lane>>5)*8+e]
__global__ void convert_w(const float* __restrict__ w1, const float* __restrict__ w2,
                          const float* __restrict__ w3, const float* __restrict__ w4,
                          bf16* __restrict__ wp) {
    const int gid = blockIdx.x * 256 + threadIdx.x;   // 0..32767
    const int e8  = gid * 8;                          // linear over 4*65536 elems
    const int blk = e8 >> 16;
    const int off = e8 & 65535;
    const int row = off >> 8;
    const int col = off & 255;
    const float* src = (blk == 0) ? w1 : (blk == 1) ? w2 : (blk == 2) ? w3 : w4;
    const float4 f0 = *(const float4*)(src + off);        // coalesced reads
    const float4 f1 = *(const float4*)(src + off + 4);
    bf16x8 o;
    o[0] = (bf16)f0.x; o[1] = (bf16)f0.y; o[2] = (bf16)f0.z; o[3] = (bf16)f0.w;
    o[4] = (bf16)f1.x; o[5] = (bf16)f1.y; o[6] = (bf16)f1.z; o[7] = (bf16)f1.w;
    const int wv = row >> 6, pair = (row >> 5) & 1, l31 = row & 31;
    const int k = col >> 4, lh = (col >> 3) & 1;
    wp += (((size_t)(blk * 4 + wv) * 16 + k) * 1024) + pair * 512 + (lh * 32 + l31) * 8;
    *(bf16x8*)wp = o;
}

#define MFMA(A, B, C) __builtin_amdgcn_mfma_f32_32x32x16_bf16(A, B, C, 0, 0, 0)

__global__ __launch_bounds__(256, 4) void ode_mfma(
    const float* __restrict__ x, const float* __restrict__ Amat,
    const bf16* __restrict__ wp,
    const float* __restrict__ b1, const float* __restrict__ b2,
    const float* __restrict__ b3, const float* __restrict__ b4,
    float* __restrict__ out)
{
    __shared__ __attribute__((aligned(16))) char smem[SMEM_BYTES];
    bf16*  sres  = (bf16*)(smem + OFF_SRES);    // [c][RS]
    bf16*  syT   = (bf16*)(smem + OFF_SYT);     // [v][YS]
    bf16*  sAb   = (bf16*)(smem + OFF_SAB);     // [v][32]
    float* sbias = (float*)(smem + OFF_SBIAS);  // [4][CC]

    const int t    = blockIdx.x;
    const int n    = blockIdx.y;
    const int tid  = threadIdx.x;
    const int wave = tid >> 6;
    const int lane = tid & 63;
    const int lh   = lane >> 5;
    const int l31  = lane & 31;
    const int o0   = wave * 64;

    // ---- blk0 w-prefetch: no LDS dependency, issue before all staging so the
    //      8 global loads complete under the staging phase + barrier. ----
    bf16x8 wA[4], wB[4];
    {
        const bf16* wb0 = wp + ((size_t)wave * 16) * 1024 + lane * 8;
        #pragma unroll
        for (int q = 0; q < 4; ++q) {
            wA[q] = *(const bf16x8*)(wb0 + q * 1024);
            wB[q] = *(const bf16x8*)(wb0 + q * 1024 + 512);
        }
    }

    // ---- stage biases (coalesced) ----
    sbias[0 * CC + tid] = b1[tid];
    sbias[1 * CC + tid] = b2[tid];
    sbias[2 * CC + tid] = b3[tid];
    sbias[3 * CC + tid] = b4[tid];

    // ---- stage A, zero-padded to 32x32 ----
    for (int i = tid; i < 32 * 32; i += 256) {
        const int v = i >> 5, u = i & 31;
        sAb[i] = (v < VV && u < VV) ? (bf16)Amat[v * VV + u] : (bf16)0.f;
    }

    // ---- stage x slab (mostly-coalesced scalar; odd t breaks 8B alignment) ----
    {
        const float* xb = x + ((size_t)n * CC * TT + t) * VV;  // + c*T*V + v
        for (int i = tid; i < CC * VV; i += 256) {
            const int c = i / VV;
            const int v = i - c * VV;
            sres[c * RS + v] = (bf16)xb[(size_t)c * TT * VV + v];
        }
        #pragma unroll
        for (int u = VV; u < 32; ++u) sres[tid * RS + u] = (bf16)0.f;  // tid == c
    }
    __syncthreads();

    // A-matrix B-fragments are constant across blocks: hoist.
    const bf16x8 bfA0 = *(const bf16x8*)&sAb[l31 * 32 + lh * 8];
    const bf16x8 bfA1 = *(const bf16x8*)&sAb[l31 * 32 + 16 + lh * 8];

    for (int blk = 0; blk < 4; ++blk) {
        // ===== Phase A: yT[v][c] = sum_u res[c][u] * A[v][u]; 2 c-tiles/wave =====
        // sres rows read here are wave-local (rows [wave*64, wave*64+64) were
        // written by this wave's own epilogue): no barrier needed for sres.
        #pragma unroll
        for (int i = 0; i < 2; ++i) {
            const int ct = wave * 2 + i;
            const bf16x8 af0 = *(const bf16x8*)&sres[(ct * 32 + l31) * RS + lh * 8];
            const bf16x8 af1 = *(const bf16x8*)&sres[(ct * 32 + l31) * RS + 16 + lh * 8];
            f32x16 d = {};
            d = MFMA(af0, bfA0, d);
            d = MFMA(af1, bfA1, d);
            // D: col v = l31, row c = ct*32 + (reg&3) + 8*(reg>>2) + 4*lh
            if (l31 < VV) {
                #pragma unroll
                for (int g = 0; g < 4; ++g) {
                    bf16x4 p;
                    p[0] = (bf16)d[4 * g];     p[1] = (bf16)d[4 * g + 1];
                    p[2] = (bf16)d[4 * g + 2]; p[3] = (bf16)d[4 * g + 3];
                    *(bf16x4*)&syT[l31 * YS + ct * 32 + 8 * g + 4 * lh] = p;
                }
            }
        }
        __syncthreads();   // barrier1: syT writes -> k-loop reads

        // ===== Phase G: out[o][v] = relu(sum_c w[o,c] y[c][v] + b[o] + res[o][v]) =====
        // Software pipeline: w rotated depth-4 (prefetched last iter), y depth-4.
        const bf16* wbase = wp + ((size_t)(blk * 4 + wave) * 16) * 1024 + lane * 8;

        f32x16 acc0 = {}, acc1 = {};
        bf16x8 yv[4];
        #pragma unroll
        for (int q = 0; q < 4; ++q)
            yv[q] = *(const bf16x8*)&syT[l31 * YS + q * 16 + lh * 8];

        __builtin_amdgcn_s_setprio(1);   // T5: 4 indep WGs/CU at different
                                         // phases -> favor the MFMA-busy wave
        #pragma unroll
        for (int k = 0; k < 16; ++k) {
            const bf16x8 a0 = wA[k & 3];
            const bf16x8 a1 = wB[k & 3];
            const bf16x8 y0 = yv[k & 3];
            if (k < 12) {   // static after full unroll -> registers, no scratch
                wA[k & 3] = *(const bf16x8*)(wbase + (k + 4) * 1024);
                wB[k & 3] = *(const bf16x8*)(wbase + (k + 4) * 1024 + 512);
                yv[k & 3] = *(const bf16x8*)&syT[l31 * YS + (k + 4) * 16 + lh * 8];
            }
            acc0 = MFMA(a0, y0, acc0);
            acc1 = MFMA(a1, y0, acc1);
        }
        __builtin_amdgcn_s_setprio(0);
        __syncthreads();   // barrier2: syT reads done -> next Phase A may write.
                           // Epilogue + next-w-prefetch + Phase A overlap across
                           // waves inside this window.

        // ---- prefetch next block's w: L2 latency hides under the epilogue ----
        if (blk < 3) {
            const bf16* wn = wp + ((size_t)((blk + 1) * 4 + wave) * 16) * 1024 + lane * 8;
            #pragma unroll
            for (int q = 0; q < 4; ++q) {
                wA[q] = *(const bf16x8*)(wn + q * 1024);
                wB[q] = *(const bf16x8*)(wn + q * 1024 + 512);
            }
        }

        const int v = l31;
        #define EPILOGUE(ACC, OT)                                                   \
            _Pragma("unroll")                                                       \
            for (int g = 0; g < 4; ++g) {                                           \
                const int ob = o0 + (OT) * 32 + 8 * g + 4 * lh;                     \
                const float4 bq = *(const float4*)&sbias[blk * CC + ob];            \
                _Pragma("unroll")                                                   \
                for (int r = 0; r < 4; ++r) {                                       \
                    const int o = ob + r;                                           \
                    float val = ACC[4 * g + r] + ((const float*)&bq)[r]             \
                              + (float)sres[o * RS + v];                            \
                    val = fmaxf(val, 0.f);                                          \
                    if (v < VV) {                                                   \
                        if (blk < 3) sres[o * RS + v] = (bf16)val;                  \
                        else out[(((size_t)n * CC + o) * TT + t) * VV + v] = val;   \
                    }                                                               \
                }                                                                   \
            }
        EPILOGUE(acc0, 0)
        EPILOGUE(acc1, 1)
        #undef EPILOGUE
    }
}

extern "C" void kernel_launch(void* const* d_in, const int* in_sizes, int n_in,
                              void* d_out, int out_size, void* d_ws, size_t ws_size,
                              hipStream_t stream) {
    const float* x  = (const float*)d_in[1];
    const float* A  = (const float*)d_in[2];
    const float* w1 = (const float*)d_in[3];
    const float* b1 = (const float*)d_in[4];
    const float* w2 = (const float*)d_in[5];
    const float* b2 = (const float*)d_in[6];
    const float* w3 = (const float*)d_in[7];
    const float* b3 = (const float*)d_in[8];
    const float* w4 = (const float*)d_in[9];
    const float* b4 = (const float*)d_in[10];
    float* out = (float*)d_out;
    bf16* wp = (bf16*)d_ws;   // 512 KB packed w fragments

    convert_w<<<128, 256, 0, stream>>>(w1, w2, w3, w4, wp);
    dim3 grid(TT, NN);        // one WG per (n,t) slab: 4096 WGs
    ode_mfma<<<grid, 256, 0, stream>>>(x, A, wp, b1, b2, b3, b4, out);
}